// Round 9
// baseline (173.533 us; speedup 1.0000x reference)
//
#include <hip/hip_runtime.h>

typedef unsigned short u16;
typedef unsigned int u32;
typedef short bf16x8 __attribute__((ext_vector_type(8)));
typedef float f32x4 __attribute__((ext_vector_type(4)));

#define NAG 32
#define STATE 512
#define EMBED 64
#define TB 32   // samples per block; grid = 1024 = 4 blocks/CU, exactly 1 round

// d_ws bf16 layout (u16 element offsets).
#define OFF_W1L1 0
#define OFF_W2L1 32768
#define OFF_B1W  65536
#define OFF_B2L1 98304
#define OFF_W1L2 131072
#define OFF_W2L2 262144
#define WS_TOTAL 266240

__device__ __forceinline__ float bf2f(u16 u) {
    u32 i = ((u32)u) << 16; float f;
    __builtin_memcpy(&f, &i, 4); return f;
}
__device__ __forceinline__ u16 f2bf(float f) {
    u32 i; __builtin_memcpy(&i, &f, 4);
    return (u16)((i + 0x8000u) >> 16);
}
__device__ __forceinline__ bf16x8 ld8(const u16* p) {
    return *reinterpret_cast<const bf16x8*>(p);
}
__device__ __forceinline__ bf16x8 cvt8(f32x4 a, f32x4 b) {
    bf16x8 r;
#pragma unroll
    for (int i = 0; i < 4; ++i) r[i]     = (short)f2bf(a[i]);
#pragma unroll
    for (int i = 0; i < 4; ++i) r[i + 4] = (short)f2bf(b[i]);
    return r;
}
__device__ __forceinline__ void dma16(const void* g, void* l) {
    __builtin_amdgcn_global_load_lds(
        (const __attribute__((address_space(1))) u32*)g,
        (__attribute__((address_space(3))) u32*)l, 16, 0, 0);
}

__global__ __launch_bounds__(256) void cvt_weights(
    const float* __restrict__ w1l1w, const float* __restrict__ w2l1w,
    const float* __restrict__ b1w,   const float* __restrict__ b2l1w,
    const float* __restrict__ w1l2w, const float* __restrict__ w2l2w,
    u16* __restrict__ ws)
{
    int idx = blockIdx.x * 256 + threadIdx.x;
    const float* src; int off;
    if      (idx < OFF_W2L1)  { src = w1l1w; off = OFF_W1L1; }
    else if (idx < OFF_B1W)   { src = w2l1w; off = OFF_W2L1; }
    else if (idx < OFF_B2L1)  { src = b1w;   off = OFF_B1W;  }
    else if (idx < OFF_W1L2)  { src = b2l1w; off = OFF_B2L1; }
    else if (idx < OFF_W2L2)  { src = w1l2w; off = OFF_W1L2; }
    else if (idx < WS_TOTAL)  { src = w2l2w; off = OFF_W2L2; }
    else return;
    ws[idx] = f2bf(src[idx - off]);
}

__global__ __launch_bounds__(256, 4) void qmix_kernel(
    const float* __restrict__ qs,    const float* __restrict__ st,
    const u16*  __restrict__ wsb,
    const float* __restrict__ w1l1b, const float* __restrict__ w1l2b,
    const float* __restrict__ w2l1b, const float* __restrict__ w2l2b,
    const float* __restrict__ b1b,   const float* __restrict__ b2l1b,
    const float* __restrict__ b2l2w, const float* __restrict__ b2l2b,
    float* __restrict__ out)
{
    __shared__ u16  wbuf[8192];       // 16 KB staging slice; hid overlays after Phase B
    __shared__ u16  y[TB][264];       // 16.9 KB: [0:64) h1, [64:128) h2, [128:192) b1v, [192:256) hb
    __shared__ u16  qslb[TB][40];     // 2.5 KB agent_qs bf16
    __shared__ u16  w1bs[2048];       // 4 KB w1l2b bf16
    __shared__ float qacc[TB][2];     // 256 B
    __shared__ float b2wv[64];        // 256 B
    // total ~40.2 KB -> 4 blocks/CU

    const int t    = threadIdx.x;
    const int wave = t >> 6, lane = t & 63;
    const int m = lane & 15, quad = lane >> 4;
    const int sbase = blockIdx.x * TB;

    // ---- prologue staging: qs->bf16, w1l2b->bf16, b2w ----
    if (t < 64) b2wv[t] = b2l2w[t];
    if (t < 128) {
        const int r = t >> 2, h = t & 3;
        const float* qp0 = qs + (size_t)(sbase + r) * NAG + h * 8;
        f32x4 q0 = *reinterpret_cast<const f32x4*>(qp0);
        f32x4 q1 = *reinterpret_cast<const f32x4*>(qp0 + 4);
        *reinterpret_cast<bf16x8*>(&qslb[r][h * 8]) = cvt8(q0, q1);
    }
    {
        f32x4 w0 = *reinterpret_cast<const f32x4*>(w1l2b + t * 8);
        f32x4 w1 = *reinterpret_cast<const f32x4*>(w1l2b + t * 8 + 4);
        *reinterpret_cast<bf16x8*>(&w1bs[t * 8]) = cvt8(w0, w1);
    }

    // ---- Phase A: Y[32][256] = states @ WA^T; wave = 16 samples x 128 feats ----
    const int shalf = wave >> 1, fhalf = wave & 1;
    const int s0 = shalf * 16;
    const int fbase = fhalf * 128;

    const float* bgA = fhalf ? b1b   : w1l1b;
    const float* bgB = fhalf ? b2l1b : w2l1b;
    float abias[8];
#pragma unroll
    for (int tt = 0; tt < 4; ++tt) abias[tt]     = bgA[tt * 16 + m];
#pragma unroll
    for (int tt = 0; tt < 4; ++tt) abias[tt + 4] = bgB[tt * 16 + m];

    const float* sp0 = st + (size_t)(sbase + s0 + m) * STATE + quad * 8;
    const int rA = lane >> 2, cA = lane & 3;   // Phase-A staging: 16 rows/dma, 4 chunks
    const int rB = lane >> 3, cB = lane & 7;   // Phase-B staging: 8 rows/dma, 8 chunks

    f32x4 acc[8] = {};
    for (int ksl = 0; ksl < 16; ++ksl) {
        __syncthreads();   // previous slice consumed (first iter: covers prologue)
        // stage WA k-slice [256 rows][32 u16]; wave stages rows wave*64..+63
#pragma unroll
        for (int j = 0; j < 4; ++j) {
            const int row = wave * 64 + j * 16 + rA;
            const int sc  = cA ^ (row & 3) ^ ((row >> 2) & 3);
            dma16(wsb + (size_t)row * STATE + ksl * 32 + sc * 8,
                  &wbuf[(wave * 64 + j * 16) * 32 + lane * 8]);
        }
        // per-lane state fragment for this slice
        f32x4 av0 = *reinterpret_cast<const f32x4*>(sp0 + ksl * 32);
        f32x4 av1 = *reinterpret_cast<const f32x4*>(sp0 + ksl * 32 + 4);
        __builtin_amdgcn_s_waitcnt(0);
        __syncthreads();
        bf16x8 af = cvt8(av0, av1);
#pragma unroll
        for (int tt = 0; tt < 8; ++tt) {
            const int row = fbase + tt * 16 + m;
            const int lc  = quad ^ (row & 3) ^ ((row >> 2) & 3);
            bf16x8 b = ld8(&wbuf[row * 32 + lc * 8]);
            acc[tt] = __builtin_amdgcn_mfma_f32_16x16x32_bf16(af, b, acc[tt], 0, 0, 0);
        }
    }
#pragma unroll
    for (int tt = 0; tt < 8; ++tt) {
        const bool isrelu = (fhalf == 0) || (tt >= 4);   // b1v tiles linear
        const int fcol = fbase + tt * 16 + m;
#pragma unroll
        for (int r = 0; r < 4; ++r) {
            float v = acc[tt][r] + abias[tt];
            if (isrelu) v = fmaxf(v, 0.f);
            y[s0 + quad * 4 + r][fcol] = f2bf(v);
        }
    }
    __syncthreads();

    // ---- Phase B: hidden = elu(sum_a qs[s,a]*|h1 @ W1l2[a]^T + b| + b1v) ----
    const int e0 = (wave & 1) * 32;
    bf16x8 haf0 = *reinterpret_cast<const bf16x8*>(&y[s0 + m][quad * 8]);
    bf16x8 haf1 = *reinterpret_cast<const bf16x8*>(&y[s0 + m][32 + quad * 8]);

    f32x4 hacc[2] = {};
    for (int bs = 0; bs < 16; ++bs) {
        __syncthreads();   // previous slice consumed (first iter: Phase-A wbuf reads done)
        // stage 2 agents = 128 rows x 64 u16 (16 KB); wave stages rows wave*32..+31
#pragma unroll
        for (int j = 0; j < 4; ++j) {
            const int row = wave * 32 + j * 8 + rB;   // slice-local row
            const int sc  = cB ^ (row & 7);
            dma16(wsb + OFF_W1L2 + ((size_t)bs * 128 + row) * EMBED + sc * 8,
                  &wbuf[(wave * 32 + j * 8) * 64 + lane * 8]);
        }
        __builtin_amdgcn_s_waitcnt(0);
        __syncthreads();
#pragma unroll
        for (int aloc = 0; aloc < 2; ++aloc) {
            float qv[4];
#pragma unroll
            for (int r = 0; r < 4; ++r)
                qv[r] = bf2f(qslb[s0 + quad * 4 + r][bs * 2 + aloc]);
#pragma unroll
            for (int tp = 0; tp < 2; ++tp) {
                const int row = aloc * 64 + e0 + tp * 16 + m;
                bf16x8 b0 = ld8(&wbuf[row * 64 + ((quad) ^ (row & 7)) * 8]);
                bf16x8 b1 = ld8(&wbuf[row * 64 + ((4 + quad) ^ (row & 7)) * 8]);
                f32x4 p = {};
                p = __builtin_amdgcn_mfma_f32_16x16x32_bf16(haf0, b0, p, 0, 0, 0);
                p = __builtin_amdgcn_mfma_f32_16x16x32_bf16(haf1, b1, p, 0, 0, 0);
                const float bias = bf2f(w1bs[(bs * 2 + aloc) * EMBED + e0 + tp * 16 + m]);
#pragma unroll
                for (int r = 0; r < 4; ++r)
                    hacc[tp][r] += qv[r] * fabsf(p[r] + bias);
            }
        }
    }
    __syncthreads();   // all waves done with wbuf -> overlay hid
    u16* hid = wbuf;   // [32][66]
#pragma unroll
    for (int tp = 0; tp < 2; ++tp) {
#pragma unroll
        for (int r = 0; r < 4; ++r) {
            const int s = s0 + quad * 4 + r, e = e0 + tp * 16 + m;
            float v = hacc[tp][r] + bf2f(y[s][128 + e]);
            v = (v > 0.f) ? v : (__expf(v) - 1.f);
            hid[s * 66 + e] = f2bf(v);
        }
    }
    __syncthreads();

    // ---- Phase C: w2 = |h2 @ W2l2^T + b|; partial q = sum_e hidden*w2 ----
    bf16x8 h2f0 = *reinterpret_cast<const bf16x8*>(&y[s0 + m][64 + quad * 8]);
    bf16x8 h2f1 = *reinterpret_cast<const bf16x8*>(&y[s0 + m][96 + quad * 8]);

    f32x4 qp = {};
#pragma unroll
    for (int tp = 0; tp < 2; ++tp) {
        const int etile = (wave & 1) * 2 + tp;
        const u16* wc = wsb + OFF_W2L2 + (size_t)(etile * 16 + m) * EMBED + quad * 8;
        bf16x8 b0 = ld8(wc);
        bf16x8 b1 = ld8(wc + 32);
        f32x4 p = {};
        p = __builtin_amdgcn_mfma_f32_16x16x32_bf16(h2f0, b0, p, 0, 0, 0);
        p = __builtin_amdgcn_mfma_f32_16x16x32_bf16(h2f1, b1, p, 0, 0, 0);
        const float bias = w2l2b[etile * 16 + m];
#pragma unroll
        for (int r = 0; r < 4; ++r)
            qp[r] += bf2f(hid[(s0 + quad * 4 + r) * 66 + etile * 16 + m]) * fabsf(p[r] + bias);
    }
#pragma unroll
    for (int off = 1; off < 16; off <<= 1) {
#pragma unroll
        for (int r = 0; r < 4; ++r) qp[r] += __shfl_xor(qp[r], off, 64);
    }
    if (m == 0) {
#pragma unroll
        for (int r = 0; r < 4; ++r) qacc[s0 + quad * 4 + r][wave & 1] = qp[r];
    }
    __syncthreads();

    // ---- Phase D: b2 + final sum (LDS-only) ----
    if (t < TB) {
        float q = qacc[t][0] + qacc[t][1] + b2l2b[0];
        float acc2 = 0.f;
#pragma unroll
        for (int kk = 0; kk < 8; ++kk) {
            bf16x8 hv = *reinterpret_cast<const bf16x8*>(&y[t][192 + kk * 8]);
#pragma unroll
            for (int j = 0; j < 8; ++j)
                acc2 += bf2f((u16)hv[j]) * b2wv[kk * 8 + j];
        }
        out[sbase + t] = q + acc2;
    }
}

extern "C" void kernel_launch(void* const* d_in, const int* in_sizes, int n_in,
                              void* d_out, int out_size, void* d_ws, size_t ws_size,
                              hipStream_t stream)
{
    const float* qs    = (const float*)d_in[0];
    const float* st    = (const float*)d_in[1];
    const float* w1l1w = (const float*)d_in[2];
    const float* w1l1b = (const float*)d_in[3];
    const float* w1l2w = (const float*)d_in[4];
    const float* w1l2b = (const float*)d_in[5];
    const float* w2l1w = (const float*)d_in[6];
    const float* w2l1b = (const float*)d_in[7];
    const float* w2l2w = (const float*)d_in[8];
    const float* w2l2b = (const float*)d_in[9];
    const float* b1w   = (const float*)d_in[10];
    const float* b1b   = (const float*)d_in[11];
    const float* b2l1w = (const float*)d_in[12];
    const float* b2l1b = (const float*)d_in[13];
    const float* b2l2w = (const float*)d_in[14];
    const float* b2l2b = (const float*)d_in[15];

    u16* wsb = (u16*)d_ws;

    cvt_weights<<<(WS_TOTAL + 255) / 256, 256, 0, stream>>>(
        w1l1w, w2l1w, b1w, b2l1w, w1l2w, w2l2w, wsb);

    int B = in_sizes[0] / NAG;        // 32768
    int grid = B / TB;                // 1024 = 4 blocks/CU, exactly 1 round
    qmix_kernel<<<grid, 256, 0, stream>>>(
        qs, st, wsb,
        w1l1b, w1l2b, w2l1b, w2l2b, b1b, b2l1b, b2l2w, b2l2b,
        (float*)d_out);
}

// Round 10
// 169.892 us; speedup vs baseline: 1.0214x; 1.0214x over previous
//
#include <hip/hip_runtime.h>

typedef unsigned short u16;
typedef unsigned int u32;
typedef short bf16x8 __attribute__((ext_vector_type(8)));
typedef float f32x4 __attribute__((ext_vector_type(4)));
typedef u16 u16x4 __attribute__((ext_vector_type(4)));

#define NAG 32
#define STATE 512
#define EMBED 64
#define TB 64   // grid = 512 = 2 blocks/CU

#define OFF_W1L1 0
#define OFF_W2L1 32768
#define OFF_B1W  65536
#define OFF_B2L1 98304
#define OFF_W1L2 131072
#define OFF_W2L2 262144
#define WS_TOTAL 266240

__device__ __forceinline__ float bf2f(u16 u) {
    u32 i = ((u32)u) << 16; float f;
    __builtin_memcpy(&f, &i, 4); return f;
}
__device__ __forceinline__ u16 f2bf(float f) {
    u32 i; __builtin_memcpy(&i, &f, 4);
    return (u16)((i + 0x8000u) >> 16);
}
__device__ __forceinline__ bf16x8 ld8(const u16* p) {
    return *reinterpret_cast<const bf16x8*>(p);
}
__device__ __forceinline__ bf16x8 cvt8(f32x4 a, f32x4 b) {
    bf16x8 r;
#pragma unroll
    for (int i = 0; i < 4; ++i) r[i]     = (short)f2bf(a[i]);
#pragma unroll
    for (int i = 0; i < 4; ++i) r[i + 4] = (short)f2bf(b[i]);
    return r;
}
__device__ __forceinline__ void dma16(const void* g, void* l) {
    __builtin_amdgcn_global_load_lds(
        (const __attribute__((address_space(1))) u32*)g,
        (__attribute__((address_space(3))) u32*)l, 16, 0, 0);
}

// vm-only wait: vmcnt=n, expcnt/lgkmcnt = max (no wait)
#define VMW(n) __builtin_amdgcn_s_waitcnt(0x0F70 | (n))
// raw barrier: no compiler-inserted vmcnt(0) drain
#define BARRIER() asm volatile("s_barrier" ::: "memory")

// stage WA k-slice: wave stages its 64 rows, chunk-major dest
#define STAGE_A(ksl, buf) do {                                          \
    const u16* _s = wsb + (size_t)(wave * 64 + lane) * STATE + (ksl) * 32; \
    u16* _d = &wa[buf][(wave * 64 + lane) * 8];                         \
    dma16(_s,      _d);                                                 \
    dma16(_s + 8,  _d + 2048);                                          \
    dma16(_s + 16, _d + 4096);                                          \
    dma16(_s + 24, _d + 6144);                                          \
} while (0)

// stage WB 2-agent slice (128 rows x 64 u16), chunk-major dest
#define STAGE_B(bs, buf) do {                                           \
    _Pragma("unroll")                                                   \
    for (int _j = 0; _j < 4; ++_j) {                                    \
        const int _idx = wave * 4 + _j;                                 \
        const int _c = _idx >> 1, _h = _idx & 1;                        \
        const int _r = _h * 64 + lane;                                  \
        dma16(wsb + OFF_W1L2 + ((size_t)(bs) * 128 + _r) * EMBED + _c * 8, \
              &wa[buf][(_c * 128 + _r) * 8]);                           \
    }                                                                   \
} while (0)

__global__ __launch_bounds__(256) void cvt_weights(
    const float* __restrict__ w1l1w, const float* __restrict__ w2l1w,
    const float* __restrict__ b1w,   const float* __restrict__ b2l1w,
    const float* __restrict__ w1l2w, const float* __restrict__ w2l2w,
    u16* __restrict__ ws)
{
    int idx = blockIdx.x * 256 + threadIdx.x;
    const float* src; int off;
    if      (idx < OFF_W2L1)  { src = w1l1w; off = OFF_W1L1; }
    else if (idx < OFF_B1W)   { src = w2l1w; off = OFF_W2L1; }
    else if (idx < OFF_B2L1)  { src = b1w;   off = OFF_B1W;  }
    else if (idx < OFF_W1L2)  { src = b2l1w; off = OFF_B2L1; }
    else if (idx < OFF_W2L2)  { src = w1l2w; off = OFF_W1L2; }
    else if (idx < WS_TOTAL)  { src = w2l2w; off = OFF_W2L2; }
    else return;
    ws[idx] = f2bf(src[idx - off]);
}

__global__ __launch_bounds__(256, 2) void qmix_kernel(
    const float* __restrict__ qs,    const float* __restrict__ st,
    const u16*  __restrict__ wsb,
    const float* __restrict__ w1l1b, const float* __restrict__ w1l2b,
    const float* __restrict__ w2l1b, const float* __restrict__ w2l2b,
    const float* __restrict__ b1b,   const float* __restrict__ b2l1b,
    const float* __restrict__ b2l2w, const float* __restrict__ b2l2b,
    float* __restrict__ out)
{
    __shared__ u16  wa[2][8192];      // 32 KB double-buffered staging (chunk-major)
    __shared__ u16  y[TB][264];       // 33 KB: [0:64) h1, [64:128) h2, [128:192) b1v, [192:256) hb
    __shared__ u16  qsT[NAG][72];     // 4.5 KB qs transposed [agent][sample] bf16
    __shared__ u16  w1bs[2048];       // 4 KB w1l2b bf16
    __shared__ float qacc[TB];
    __shared__ float b2wv[64];
    // total ~74 KB -> 2 blocks/CU

    const int t    = threadIdx.x;
    const int wave = t >> 6, lane = t & 63;
    const int m = lane & 15, quad = lane >> 4;
    const int sbase = blockIdx.x * TB;
    const int s0 = wave * 16;

    // ---- prologue: b2wv, w1bs, qsT (transposed), biases ----
    if (t < 64) b2wv[t] = b2l2w[t];
    {
        f32x4 w0 = *reinterpret_cast<const f32x4*>(w1l2b + t * 8);
        f32x4 w1 = *reinterpret_cast<const f32x4*>(w1l2b + t * 8 + 4);
        *reinterpret_cast<bf16x8*>(&w1bs[t * 8]) = cvt8(w0, w1);
    }
    {
        const int a = t & 31, sg = (t >> 5) * 8;
#pragma unroll
        for (int k = 0; k < 8; ++k)
            qsT[a][sg + k] = f2bf(qs[(size_t)(sbase + sg + k) * NAG + a]);
    }
    float abias[16];
#pragma unroll
    for (int tt = 0; tt < 4; ++tt) abias[tt]      = w1l1b[tt * 16 + m];
#pragma unroll
    for (int tt = 0; tt < 4; ++tt) abias[tt + 4]  = w2l1b[tt * 16 + m];
#pragma unroll
    for (int tt = 0; tt < 4; ++tt) abias[tt + 8]  = b1b[tt * 16 + m];
#pragma unroll
    for (int tt = 0; tt < 4; ++tt) abias[tt + 12] = b2l1b[tt * 16 + m];

    // ---- Phase A: Y[64][256]; wave = 16 samples x 256 feats; 16 K-slices of 32, dbuf ----
    const float* sp0 = st + (size_t)(sbase + s0 + m) * STATE + quad * 8;
    f32x4 sa0 = *reinterpret_cast<const f32x4*>(sp0);
    f32x4 sb0 = *reinterpret_cast<const f32x4*>(sp0 + 4);
    STAGE_A(0, 0);

    f32x4 acc[16] = {};
    f32x4 sa1, sb1;
    for (int s = 0; s < 16; ++s) {
        BARRIER();                       // buffer (s+1)&1 free to overwrite
        if (s < 15) {
            STAGE_A(s + 1, (s + 1) & 1);
            sa1 = *reinterpret_cast<const f32x4*>(sp0 + (s + 1) * 32);
            sb1 = *reinterpret_cast<const f32x4*>(sp0 + (s + 1) * 32 + 4);
            VMW(6);                      // slice s landed; s+1's 6 stay in flight
        } else {
            STAGE_B(0, 0);               // pre-stage Phase-B slice 0
            VMW(4);
        }
        BARRIER();                       // slice s visible to all waves
        bf16x8 af = cvt8(sa0, sb0);
        const u16* wb = wa[s & 1];
#pragma unroll
        for (int tt = 0; tt < 16; ++tt) {
            const int row = tt * 16 + m;
            bf16x8 b = ld8(&wb[(quad * 256 + row) * 8]);
            acc[tt] = __builtin_amdgcn_mfma_f32_16x16x32_bf16(af, b, acc[tt], 0, 0, 0);
        }
        sa0 = sa1; sb0 = sb1;
    }
#pragma unroll
    for (int tt = 0; tt < 16; ++tt) {
        const bool isrelu = (tt < 8) || (tt >= 12);   // tiles 8..11 = b1v (linear)
        const int fcol = tt * 16 + m;
#pragma unroll
        for (int r = 0; r < 4; ++r) {
            float v = acc[tt][r] + abias[tt];
            if (isrelu) v = fmaxf(v, 0.f);
            y[s0 + quad * 4 + r][fcol] = f2bf(v);
        }
    }
    __syncthreads();   // full drain: y visible, B0 DMA landed, prologue LDS visible

    // ---- Phase B: e-split; wave owns e = wave*16+m for all 64 samples; 16 slices, dbuf ----
    const int e = wave * 16 + m;
    bf16x8 haf[4][2];
#pragma unroll
    for (int g = 0; g < 4; ++g) {
        haf[g][0] = *reinterpret_cast<const bf16x8*>(&y[g * 16 + m][quad * 8]);
        haf[g][1] = *reinterpret_cast<const bf16x8*>(&y[g * 16 + m][32 + quad * 8]);
    }

    f32x4 hacc[4] = {};
    for (int bs = 0; bs < 16; ++bs) {
        BARRIER();
        if (bs < 15) {
            STAGE_B(bs + 1, (bs + 1) & 1);
            VMW(4);
        } else {
            VMW(0);
        }
        BARRIER();
        const u16* wb = wa[bs & 1];
#pragma unroll
        for (int aloc = 0; aloc < 2; ++aloc) {
            const int row = aloc * 64 + wave * 16 + m;
            bf16x8 b0 = ld8(&wb[(quad * 128 + row) * 8]);
            bf16x8 b1 = ld8(&wb[((4 + quad) * 128 + row) * 8]);
            const int a = bs * 2 + aloc;
            const float bias = bf2f(w1bs[a * EMBED + e]);
#pragma unroll
            for (int g = 0; g < 4; ++g) {
                f32x4 p = {};
                p = __builtin_amdgcn_mfma_f32_16x16x32_bf16(haf[g][0], b0, p, 0, 0, 0);
                p = __builtin_amdgcn_mfma_f32_16x16x32_bf16(haf[g][1], b1, p, 0, 0, 0);
                u16x4 qv = *reinterpret_cast<const u16x4*>(&qsT[a][g * 16 + quad * 4]);
#pragma unroll
                for (int r = 0; r < 4; ++r)
                    hacc[g][r] += bf2f((u16)qv[r]) * fabsf(p[r] + bias);
            }
        }
    }
    __syncthreads();   // all wa reads done -> overlay hid
    u16* hid = (u16*)wa;   // [64][66]
#pragma unroll
    for (int g = 0; g < 4; ++g)
#pragma unroll
        for (int r = 0; r < 4; ++r) {
            const int s = g * 16 + quad * 4 + r;
            float v = hacc[g][r] + bf2f(y[s][128 + e]);
            v = (v > 0.f) ? v : (__expf(v) - 1.f);
            hid[s * 66 + e] = f2bf(v);
        }
    __syncthreads();

    // ---- Phase C: w2 = |h2 @ W2l2^T + b|; q = sum_e hidden*w2 (wave owns 16 samples) ----
    bf16x8 h2f0 = *reinterpret_cast<const bf16x8*>(&y[s0 + m][64 + quad * 8]);
    bf16x8 h2f1 = *reinterpret_cast<const bf16x8*>(&y[s0 + m][96 + quad * 8]);

    f32x4 qp = {};
#pragma unroll
    for (int tp = 0; tp < 4; ++tp) {
        const u16* wc = wsb + OFF_W2L2 + (size_t)(tp * 16 + m) * EMBED + quad * 8;
        bf16x8 b0 = ld8(wc);
        bf16x8 b1 = ld8(wc + 32);
        f32x4 p = {};
        p = __builtin_amdgcn_mfma_f32_16x16x32_bf16(h2f0, b0, p, 0, 0, 0);
        p = __builtin_amdgcn_mfma_f32_16x16x32_bf16(h2f1, b1, p, 0, 0, 0);
        const float bias = w2l2b[tp * 16 + m];
#pragma unroll
        for (int r = 0; r < 4; ++r)
            qp[r] += bf2f(hid[(s0 + quad * 4 + r) * 66 + tp * 16 + m]) * fabsf(p[r] + bias);
    }
#pragma unroll
    for (int off = 1; off < 16; off <<= 1) {
#pragma unroll
        for (int r = 0; r < 4; ++r) qp[r] += __shfl_xor(qp[r], off, 64);
    }
    if (m == 0) {
#pragma unroll
        for (int r = 0; r < 4; ++r) qacc[s0 + quad * 4 + r] = qp[r];
    }
    __syncthreads();

    // ---- Phase D: b2 + final sum (LDS-only) ----
    if (t < TB) {
        float q = qacc[t] + b2l2b[0];
        float acc2 = 0.f;
#pragma unroll
        for (int kk = 0; kk < 8; ++kk) {
            bf16x8 hv = *reinterpret_cast<const bf16x8*>(&y[t][192 + kk * 8]);
#pragma unroll
            for (int j = 0; j < 8; ++j)
                acc2 += bf2f((u16)hv[j]) * b2wv[kk * 8 + j];
        }
        out[sbase + t] = q + acc2;
    }
}

extern "C" void kernel_launch(void* const* d_in, const int* in_sizes, int n_in,
                              void* d_out, int out_size, void* d_ws, size_t ws_size,
                              hipStream_t stream)
{
    const float* qs    = (const float*)d_in[0];
    const float* st    = (const float*)d_in[1];
    const float* w1l1w = (const float*)d_in[2];
    const float* w1l1b = (const float*)d_in[3];
    const float* w1l2w = (const float*)d_in[4];
    const float* w1l2b = (const float*)d_in[5];
    const float* w2l1w = (const float*)d_in[6];
    const float* w2l1b = (const float*)d_in[7];
    const float* w2l2w = (const float*)d_in[8];
    const float* w2l2b = (const float*)d_in[9];
    const float* b1w   = (const float*)d_in[10];
    const float* b1b   = (const float*)d_in[11];
    const float* b2l1w = (const float*)d_in[12];
    const float* b2l1b = (const float*)d_in[13];
    const float* b2l2w = (const float*)d_in[14];
    const float* b2l2b = (const float*)d_in[15];

    u16* wsb = (u16*)d_ws;

    cvt_weights<<<(WS_TOTAL + 255) / 256, 256, 0, stream>>>(
        w1l1w, w2l1w, b1w, b2l1w, w1l2w, w2l2w, wsb);

    int B = in_sizes[0] / NAG;        // 32768
    int grid = B / TB;                // 512 = 2 blocks/CU
    qmix_kernel<<<grid, 256, 0, stream>>>(
        qs, st, wsb,
        w1l1b, w1l2b, w2l1b, w2l2b, b1b, b2l1b, b2l2w, b2l2b,
        (float*)d_out);
}